// Round 10
// baseline (231.579 us; speedup 1.0000x reference)
//
#include <hip/hip_runtime.h>
#include <cfloat>
#include <cstddef>

// VQ-VAE vector quantizer, MI355X / gfx950.
// z: (32, 64, 32, 32) f32 BCHW; embedding: (1024, 64) f32.
// Outputs concatenated f32: loss[1], z_q(BCHW)[2097152], perplexity[1],
// min_encodings[32768*1024], min_encoding_indices(as float)[32768].
//
// Structure history (measured):
//   R1 (108us): rows/lane, codes s_load, disjoint streams -> VALU 37%.
//   R2 (284us): uniform-addr vector loads -> 64x RF replication.
//   R3 (154us): rows LDS-broadcast -> LDS return-bw bound.
//   R4 (181us): rows scalar-streamed at 4KB stride -> SMEM issue storm.
//   R5 (137us): quad-sliced codes -> reduction inst bloat.
//   R6 (199us): 4 codes/lane resident -> RF overflow, 1 wave/SIMD.
//   R7 (scan 91us, VALU 45%): scan/epi split, 4-wave convoyed scalar
//     streams. Cycle model fits ONLY if the inner loop is ~150cyc/code,
//     i.e. the v2f elementwise_fma SCALARIZED (building v2f from SGPR
//     components costs 2 v_mov + pk = 3 inst, so the compiler emitted
//     64 v_fma_f32 with free SGPR operands instead).
//   R8 (scan 102us): stagger broke sL1 line sharing -> worse.
//   R9 (scan ~75us inferred; counters swamped by the harness's ~85us
//     output-restore fills that sit INSIDE the timed region -- the fixed
//     ~105us/round overhead is mostly that restore, not ours).
//   R10 (this): two multiplicative fixes on the R7 skeleton:
//     (a) REAL v_pk_fma_f32 via inline asm, codebook as u64 pairs in
//         SGPRs (SGPR src0 legal: 1 SGPR/VALU inst) -> ~80cyc/code;
//     (b) 8-sharer convoy: block = 512 rows x ONE 128-code chunk, all 8
//         waves stream the same lines, s_barrier every 32 codes ->
//         first-touch L2 miss amortized 8 ways (~62cyc avg).
//     Plus: hist zeroing folded into vq_e2 (one less dispatch); code
//     addresses blockIdx-derived -> provably uniform s_load.
//
// Numerics (must match the absmax-0.0 lineage bit-for-bit):
//   dot: v_pk_fma_f32 lane-element semantics = fmaf per element (no
//     op_sel): accA over even pairs (c%4 in {0,1}), accB over odd pairs
//     (c%4 in {2,3}), k ascending -> accA = (a0,a1), accB = (a2,a3);
//     dot = (a0+a1)+(a2+a3). Exactly the reference chains.
//   e2/z2: sequential double accumulation (ch ascending), rounded once.
//   d = (z2f + e2f) - 2.0f*dot (two fp32 roundings at magnitude ~64).
//   argmin: wave scans its 128-code chunk ascending with strict <
//     (first index); epilogue combines the 8 chunk candidates in
//     ascending-chunk order with strict < -> exact np.argmin semantics.
//   loss: epilogue reproduces R1's partial[512] tree verbatim; vq_final
//     unchanged.

#define NROWS 32768
#define NE    1024
#define EDIM  64
#define TPB_A 512
#define GRID_A 512            // 64 row-blocks (512 rows) x 8 code-chunks
#define TPB_B 256
#define GRID_B 512            // 64 rows each
#define NPART 512

#define OFF_LOSS ((size_t)0)
#define OFF_ZQ   ((size_t)1)
#define OFF_PERP ((size_t)2097153)
#define OFF_OH   ((size_t)2097154)
#define OFF_IDX  ((size_t)35651586)

typedef float v2f __attribute__((ext_vector_type(2)));
typedef unsigned long long u64;

// ws layout (bytes): [0,4096) int hist[1024]; [4096,6144) float partial[512];
//                    [8192,12288) float e2buf[1024]

__global__ __launch_bounds__(128) void vq_e2(const float* __restrict__ emb,
                                             float* __restrict__ e2buf,
                                             int* __restrict__ hist) {
    int j = blockIdx.x * 128 + threadIdx.x;          // grid 8x128 = 1024
    hist[j] = 0;                                     // replaces hipMemsetAsync
    const float* e = emb + ((size_t)j << 6);
    double s = 0.0;
#pragma unroll
    for (int c = 0; c < EDIM; ++c) { float v = e[c]; s += (double)v * (double)v; }
    e2buf[j] = (float)s;
}

__global__ __launch_bounds__(TPB_A, 4) void vq_scan(const float* __restrict__ z,
                                                    const float* __restrict__ emb,
                                                    const float* __restrict__ e2buf,
                                                    float* __restrict__ out) {
    const int t    = threadIdx.x;
    const int lane = t & 63;
    const int q    = t >> 6;                 // wave 0..7 = row group
    const int rb   = blockIdx.x >> 3;        // row-block 0..63
    const int cb   = blockIdx.x & 7;         // code-chunk 0..7
    const int r0   = rb << 9;                // 512 rows per block

    const int row  = r0 + (q << 6) + lane;   // this lane's row
    const int b    = row >> 10;
    const int m    = row & 1023;
    const size_t zbase = (size_t)b * 65536 + (size_t)m;

    // ---- this lane's z row (64 ch, stride 1024) + ||z||^2 -----------------
    v2f zp[32];
    double sd = 0.0;
#pragma unroll
    for (int n = 0; n < 32; ++n) {
        float x = z[zbase + (size_t)(2 * n) * 1024];
        float y = z[zbase + (size_t)(2 * n + 1) * 1024];
        zp[n] = (v2f){x, y};
        sd += (double)x * (double)x;         // c ascending: 2n then 2n+1
        sd += (double)y * (double)y;
    }
    const float z2f = (float)sd;             // consumes loads -> vmcnt drains

    // ---- fire-and-forget zero-fill: rows [r0,+512) x cols [128cb,+128) ----
    // 256 KB. The scan below is SMEM/VALU only (no vmem waits; raw
    // s_barriers wait nothing) -> these stores drain under the compute.
    // The 1.0f scatter in vq_epi is ordered after them by the KERNEL
    // BOUNDARY.
    {
        float* basep = out + OFF_OH + (size_t)r0 * 1024 + (cb << 7);
        for (int i = t; i < 32768; i += TPB_A) {
            int r  = i >> 6;                 // 0..511
            int c2 = i & 63;                 // float2 column within 128 cols
            *(float2*)(basep + (size_t)r * 1024 + 2 * c2) = make_float2(0.f, 0.f);
        }
    }

    // ---- scan this block's 128-code chunk: 8-wave convoyed scalar stream --
    // Code addresses derive only from blockIdx/loop -> provably uniform ->
    // s_load (s_load_dwordx16 x4 per code). All 8 waves read the SAME lines;
    // s_barrier every 32 codes keeps the convoy tight (R7-proven; R8 proved
    // staggering destroys the sharing). First-touch L2 miss amortized 8x.
    const int jf = cb << 7;
    float bestd = FLT_MAX;
    int   bestj = NE;
    for (int jj = 0; jj < 128; ++jj) {
        const int j = jf + jj;
        const u64* ep = (const u64*)(emb + ((size_t)j << 6));  // 32 u64 pairs
        const float e2f = e2buf[j];          // s_load (uniform)
        u64 es[32];
#pragma unroll
        for (int k = 0; k < 32; ++k) es[k] = ep[k];
        // packed fp32 fma: accA over even pairs (chains a0,a1), accB over
        // odd pairs (a2,a3), k ascending. SGPR pair as src0 (1 SGPR/inst).
        v2f accA = {0.f, 0.f}, accB = {0.f, 0.f};
#pragma unroll
        for (int k = 0; k < 16; ++k) {
            asm("v_pk_fma_f32 %0, %1, %2, %0"
                : "+v"(accA) : "s"(es[2 * k]), "v"(zp[2 * k]));
            asm("v_pk_fma_f32 %0, %1, %2, %0"
                : "+v"(accB) : "s"(es[2 * k + 1]), "v"(zp[2 * k + 1]));
        }
        float dot = (accA.x + accA.y) + (accB.x + accB.y);
        float d   = (z2f + e2f) - 2.0f * dot;
        if (d < bestd) { bestd = d; bestj = j; }     // ascending: first index
        if ((jj & 31) == 31) __builtin_amdgcn_s_barrier();   // convoy re-sync
    }

    // ---- stash candidate (d, j) in the z_q region, channels 2cb, 2cb+1 ----
    // Each row is scanned by exactly one wave per chunk -> direct stash, no
    // combine. vq_epi reads these BEFORE overwriting the region with z_q.
    out[OFF_ZQ + zbase + (size_t)(2 * cb) * 1024]     = bestd;
    out[OFF_ZQ + zbase + (size_t)(2 * cb + 1) * 1024] = __int_as_float(bestj);
}

__global__ __launch_bounds__(TPB_B) void vq_epi(const float* __restrict__ z,
                                                const float* __restrict__ emb,
                                                int* __restrict__ hist,
                                                float* __restrict__ partial,
                                                float* __restrict__ out) {
    const int t    = threadIdx.x;
    const int lane = t & 63;
    const int q    = t >> 6;                 // wave 0..3
    const int r0   = blockIdx.x << 6;        // 64 rows per block

    __shared__ int   s_idx[64];
    __shared__ float s_l[8];

    // ---- combine 8 chunk candidates per row (ascending chunk = ascending
    //      code range; strict < keeps the first/lowest index) --------------
    if (t < 64) {
        const int row = r0 + t;
        const int b   = row >> 10;
        const int m   = row & 1023;
        const size_t zbase = (size_t)b * 65536 + (size_t)m;
        const float* cp = out + OFF_ZQ + zbase;
        float bd = cp[0];
        int   bj = __float_as_int(cp[1024]);
#pragma unroll
        for (int gc = 1; gc < 8; ++gc) {
            float d = cp[(size_t)(2 * gc) * 1024];
            int   j = __float_as_int(cp[(size_t)(2 * gc + 1) * 1024]);
            if (d < bd) { bd = d; bj = j; }
        }
        s_idx[t] = bj;
        out[OFF_IDX + row] = (float)bj;                       // index as float
        out[OFF_OH + (size_t)row * 1024 + bj] = 1.0f;         // one-hot scatter
        atomicAdd(&hist[bj], 1);
    }
    __syncthreads();   // candidates of ALL rows read before z_q overwrites

    // ---- z_q (straight-through) + loss partial: R1's tree verbatim -------
    // wave q handles classes {q, q+4}; chains c = cls + 8i (i ascending),
    // shfl_down butterfly, s_l[8] summed ascending -> partial[512]
    // bit-identical to the R1 lineage; vq_final unchanged.
    {
        const int row = r0 + lane;
        const int b   = row >> 10;
        const int m   = row & 1023;
        const size_t zbr = (size_t)b * 65536 + (size_t)m;
        const int    jjx = s_idx[lane];
        const float* er  = emb + ((size_t)jjx << 6);
        float* zq = out + OFF_ZQ + zbr;
#pragma unroll
        for (int p = 0; p < 2; ++p) {
            const int cls = q + 4 * p;
            float ls = 0.f;
#pragma unroll
            for (int i = 0; i < 8; ++i) {
                int c = cls + 8 * i;
                float zc   = z[zbr + (size_t)c * 1024];       // coalesced
                float ev   = er[c];                           // gather (L2)
                float diff = ev - zc;
                zq[(size_t)c * 1024] = zc + diff;             // zp + (z_q-zp)
                ls = fmaf(diff, diff, ls);
            }
#pragma unroll
            for (int off = 32; off >= 1; off >>= 1) ls += __shfl_down(ls, off);
            if (lane == 0) s_l[cls] = ls;
        }
        __syncthreads();
        if (t == 0) {
            float l = 0.f;
#pragma unroll
            for (int c = 0; c < 8; ++c) l += s_l[c];          // ascending
            partial[blockIdx.x] = l;
        }
    }
}

__global__ __launch_bounds__(1024) void vq_final(const int* __restrict__ hist,
                                                 const float* __restrict__ partial,
                                                 float* __restrict__ out) {
    int t = threadIdx.x;
    float p    = (float)hist[t] * (1.0f / 32768.0f);
    float term = p * logf(p + 1e-10f);
    float lp   = (t < NPART) ? partial[t] : 0.f;
#pragma unroll
    for (int off = 32; off >= 1; off >>= 1) {
        term += __shfl_down(term, off);
        lp   += __shfl_down(lp, off);
    }
    __shared__ float st[16], sl[16];
    int w = t >> 6, ln = t & 63;
    if (ln == 0) { st[w] = term; sl[w] = lp; }
    __syncthreads();
    if (t == 0) {
        float s = 0.f, l = 0.f;
#pragma unroll
        for (int i = 0; i < 16; ++i) { s += st[i]; l += sl[i]; }
        out[OFF_LOSS] = 1.25f * l * (1.0f / 2097152.0f);  // (1+beta)*mean
        out[OFF_PERP] = expf(-s);
    }
}

extern "C" void kernel_launch(void* const* d_in, const int* in_sizes, int n_in,
                              void* d_out, int out_size, void* d_ws, size_t ws_size,
                              hipStream_t stream) {
    const float* z   = (const float*)d_in[0];
    const float* emb = (const float*)d_in[1];
    float* out     = (float*)d_out;
    int*   hist    = (int*)d_ws;
    float* partial = (float*)((char*)d_ws + 4096);
    float* e2buf   = (float*)((char*)d_ws + 8192);

    vq_e2<<<8, 128, 0, stream>>>(emb, e2buf, hist);
    vq_scan<<<GRID_A, TPB_A, 0, stream>>>(z, emb, e2buf, out);
    vq_epi<<<GRID_B, TPB_B, 0, stream>>>(z, emb, hist, partial, out);
    vq_final<<<1, 1024, 0, stream>>>(hist, partial, out);
}

// Round 11
// 228.780 us; speedup vs baseline: 1.0122x; 1.0122x over previous
//
#include <hip/hip_runtime.h>
#include <cfloat>
#include <cstddef>

// VQ-VAE vector quantizer, MI355X / gfx950.
// z: (32, 64, 32, 32) f32 BCHW; embedding: (1024, 64) f32.
// Outputs concatenated f32: loss[1], z_q(BCHW)[2097152], perplexity[1],
// min_encodings[32768*1024], min_encoding_indices(as float)[32768].
//
// Structure history (measured):
//   R1-R6: delivery-path search (scalar stream wins; vector/LDS broadcast
//     pay 64x lane replication; resident codes overflow the RF).
//   R7 (scan 91us, VALU 45%), R8 (102us, stagger refuted), R9 (scan ~75us
//     at 5 waves/SIMD), R10 (93us, asm pk_fma NO effect).
//   DIAGNOSIS (fits R7==R10 exactly): VGPR_Count=40 both rounds, yet the
//     loop consumes a 64-float z-row per code -> the compiler DEMOTED the
//     arrayed zp[] to AGPRs (unified RF; not in VGPR_Count), inserting
//     v_accvgpr_read before every use: ~64 hidden moves/code. Packed vs
//     scalar fma was therefore ~100 insts/code either way -> identical
//     time. The scan has been paying a 2x VALU tax since R7.
//   R11 (this): remove the demotion, keep everything proven:
//     (a) hot state in NAMED locals (z0..z31 v2f, e0..e31 u64), all uses
//         compile-time-constant via macros -> nothing to demote (rule-#20
//         class fix);
//     (b) TPB 256, launch_bounds(256,4), grid 1024 = 128 rowgroups(256
//         rows) x 8 chunks -> 4 blocks/CU = 4 waves/SIMD, VGPR cap 128
//         (z row ~64 + temps fits as arch VGPRs);
//     (c) R7's proven convoy: 4 waves/block march one 32KB chunk with
//         s_barrier every 32 codes (R8 proved staggering is worse);
//     (d) asm v_pk_fma_f32 with SGPR-pair src0 (R10-proven numerics).
//
// Numerics (must match the absmax-0.0 lineage bit-for-bit):
//   dot: accA elt-x/y = chains a0/a1 (channels ==0/1 mod 4), accB = a2/a3,
//     k ascending; dot = (accA.x+accA.y)+(accB.x+accB.y) = (a0+a1)+(a2+a3).
//     v_pk_fma_f32 element rounding == fmaf. Proven exact R10.
//   e2/z2: sequential double accumulation (ch ascending), rounded once.
//   d = (z2f + e2f) - 2.0f*dot (two fp32 roundings at magnitude ~64).
//   argmin: wave scans its 128-code chunk ascending with strict <
//     (first index); epilogue combines the 8 chunk candidates in
//     ascending-chunk order with strict < -> exact np.argmin semantics.
//   loss: epilogue reproduces R1's partial[512] tree verbatim; vq_final
//     unchanged.

#define NROWS 32768
#define NE    1024
#define EDIM  64
#define TPB_A 256
#define GRID_A 1024           // 128 rowgroups (256 rows) x 8 code-chunks
#define TPB_B 256
#define GRID_B 512            // 64 rows each
#define NPART 512

#define OFF_LOSS ((size_t)0)
#define OFF_ZQ   ((size_t)1)
#define OFF_PERP ((size_t)2097153)
#define OFF_OH   ((size_t)2097154)
#define OFF_IDX  ((size_t)35651586)

typedef float v2f __attribute__((ext_vector_type(2)));
typedef unsigned long long u64;

// ws layout (bytes): [0,4096) int hist[1024]; [4096,6144) float partial[512];
//                    [8192,12288) float e2buf[1024]

__global__ __launch_bounds__(128) void vq_e2(const float* __restrict__ emb,
                                             float* __restrict__ e2buf,
                                             int* __restrict__ hist) {
    int j = blockIdx.x * 128 + threadIdx.x;          // grid 8x128 = 1024
    hist[j] = 0;                                     // replaces hipMemsetAsync
    const float* e = emb + ((size_t)j << 6);
    double s = 0.0;
#pragma unroll
    for (int c = 0; c < EDIM; ++c) { float v = e[c]; s += (double)v * (double)v; }
    e2buf[j] = (float)s;
}

// ---- named-local machinery (no arrays -> no AGPR/scratch demotion) -------
#define LDZ(i)                                                                \
    v2f z##i;                                                                 \
    {                                                                         \
        float x_ = zrp[(size_t)(2 * (i)) * 1024];                             \
        float y_ = zrp[(size_t)(2 * (i) + 1) * 1024];                         \
        z##i = (v2f){x_, y_};                                                 \
        sd += (double)x_ * (double)x_;                                        \
        sd += (double)y_ * (double)y_;                                        \
    }

#define LDE(i) const u64 e##i = ep[i];

#define PKA(i) asm("v_pk_fma_f32 %0, %1, %2, %0" : "+v"(accA) : "s"(e##i), "v"(z##i));
#define PKB(i) asm("v_pk_fma_f32 %0, %1, %2, %0" : "+v"(accB) : "s"(e##i), "v"(z##i));

__global__ __launch_bounds__(TPB_A, 4) void vq_scan(const float* __restrict__ z,
                                                    const float* __restrict__ emb,
                                                    const float* __restrict__ e2buf,
                                                    float* __restrict__ out) {
    const int t    = threadIdx.x;
    const int lane = t & 63;
    const int q    = t >> 6;                 // wave 0..3 = row group
    const int rg   = blockIdx.x >> 3;        // rowgroup 0..127
    const int cb   = blockIdx.x & 7;         // code-chunk 0..7
    const int r0   = rg << 8;                // 256 rows per block

    const int row  = r0 + (q << 6) + lane;   // this lane's row
    const int b    = row >> 10;
    const int m    = row & 1023;
    const size_t zbase = (size_t)b * 65536 + (size_t)m;

    // ---- this lane's z row: 32 NAMED v2f (channels 2i, 2i+1) + ||z||^2 ----
    const float* zrp = z + zbase;
    double sd = 0.0;
    LDZ(0)  LDZ(1)  LDZ(2)  LDZ(3)  LDZ(4)  LDZ(5)  LDZ(6)  LDZ(7)
    LDZ(8)  LDZ(9)  LDZ(10) LDZ(11) LDZ(12) LDZ(13) LDZ(14) LDZ(15)
    LDZ(16) LDZ(17) LDZ(18) LDZ(19) LDZ(20) LDZ(21) LDZ(22) LDZ(23)
    LDZ(24) LDZ(25) LDZ(26) LDZ(27) LDZ(28) LDZ(29) LDZ(30) LDZ(31)
    const float z2f = (float)sd;             // consumes loads -> vmcnt drains

    // ---- fire-and-forget zero-fill: rows [r0,+256) x cols [128cb,+128) ----
    // 128 KB contiguous columns slice. Scan below is SMEM/VALU only (raw
    // barriers wait nothing) -> stores drain under compute; the 1.0f scatter
    // in vq_epi is ordered after them by the KERNEL BOUNDARY.
    {
        float* basep = out + OFF_OH + (size_t)r0 * 1024 + (cb << 7);
        for (int i = t; i < 16384; i += TPB_A) {
            int r  = i >> 6;                 // 0..255
            int c2 = i & 63;                 // float2 column within 128 cols
            *(float2*)(basep + (size_t)r * 1024 + 2 * c2) = make_float2(0.f, 0.f);
        }
    }

    // ---- scan this block's 128-code chunk: 4-wave convoyed scalar stream --
    // Code addresses derive only from blockIdx/loop -> provably uniform ->
    // s_load (4x s_load_dwordx16 per code into 32 named u64 SGPR pairs).
    // All 4 waves read the SAME lines; s_barrier every 32 codes keeps the
    // convoy tight (R7-proven). 4 chunk-streams per CU.
    const int jf = cb << 7;
    float bestd = FLT_MAX;
    int   bestj = NE;
    for (int jj = 0; jj < 128; ++jj) {
        const int j = jf + jj;
        const u64* ep = (const u64*)(emb + ((size_t)j << 6));  // 32 u64 pairs
        const float e2f = e2buf[j];          // s_load_dword (uniform)
        LDE(0)  LDE(1)  LDE(2)  LDE(3)  LDE(4)  LDE(5)  LDE(6)  LDE(7)
        LDE(8)  LDE(9)  LDE(10) LDE(11) LDE(12) LDE(13) LDE(14) LDE(15)
        LDE(16) LDE(17) LDE(18) LDE(19) LDE(20) LDE(21) LDE(22) LDE(23)
        LDE(24) LDE(25) LDE(26) LDE(27) LDE(28) LDE(29) LDE(30) LDE(31)
        // packed fp32 fma: accA over even pairs (chains a0,a1), accB over
        // odd pairs (a2,a3), k ascending. SGPR pair is src0 (1 SGPR/inst).
        v2f accA = {0.f, 0.f}, accB = {0.f, 0.f};
        PKA(0)  PKB(1)  PKA(2)  PKB(3)  PKA(4)  PKB(5)  PKA(6)  PKB(7)
        PKA(8)  PKB(9)  PKA(10) PKB(11) PKA(12) PKB(13) PKA(14) PKB(15)
        PKA(16) PKB(17) PKA(18) PKB(19) PKA(20) PKB(21) PKA(22) PKB(23)
        PKA(24) PKB(25) PKA(26) PKB(27) PKA(28) PKB(29) PKA(30) PKB(31)
        float dot = (accA.x + accA.y) + (accB.x + accB.y);
        float d   = (z2f + e2f) - 2.0f * dot;
        if (d < bestd) { bestd = d; bestj = j; }     // ascending: first index
        if ((jj & 31) == 31) __builtin_amdgcn_s_barrier();   // convoy re-sync
    }

    // ---- stash candidate (d, j) in the z_q region, channels 2cb, 2cb+1 ----
    // Each row is scanned by exactly one wave per chunk -> direct stash.
    // vq_epi reads these BEFORE overwriting the region with z_q.
    out[OFF_ZQ + zbase + (size_t)(2 * cb) * 1024]     = bestd;
    out[OFF_ZQ + zbase + (size_t)(2 * cb + 1) * 1024] = __int_as_float(bestj);
}

__global__ __launch_bounds__(TPB_B) void vq_epi(const float* __restrict__ z,
                                                const float* __restrict__ emb,
                                                int* __restrict__ hist,
                                                float* __restrict__ partial,
                                                float* __restrict__ out) {
    const int t    = threadIdx.x;
    const int lane = t & 63;
    const int q    = t >> 6;                 // wave 0..3
    const int r0   = blockIdx.x << 6;        // 64 rows per block

    __shared__ int   s_idx[64];
    __shared__ float s_l[8];

    // ---- combine 8 chunk candidates per row (ascending chunk = ascending
    //      code range; strict < keeps the first/lowest index) --------------
    if (t < 64) {
        const int row = r0 + t;
        const int b   = row >> 10;
        const int m   = row & 1023;
        const size_t zbase = (size_t)b * 65536 + (size_t)m;
        const float* cp = out + OFF_ZQ + zbase;
        float bd = cp[0];
        int   bj = __float_as_int(cp[1024]);
#pragma unroll
        for (int gc = 1; gc < 8; ++gc) {
            float d = cp[(size_t)(2 * gc) * 1024];
            int   j = __float_as_int(cp[(size_t)(2 * gc + 1) * 1024]);
            if (d < bd) { bd = d; bj = j; }
        }
        s_idx[t] = bj;
        out[OFF_IDX + row] = (float)bj;                       // index as float
        out[OFF_OH + (size_t)row * 1024 + bj] = 1.0f;         // one-hot scatter
        atomicAdd(&hist[bj], 1);
    }
    __syncthreads();   // candidates of ALL rows read before z_q overwrites

    // ---- z_q (straight-through) + loss partial: R1's tree verbatim -------
    // wave q handles classes {q, q+4}; chains c = cls + 8i (i ascending),
    // shfl_down butterfly, s_l[8] summed ascending -> partial[512]
    // bit-identical to the R1 lineage; vq_final unchanged.
    {
        const int row = r0 + lane;
        const int b   = row >> 10;
        const int m   = row & 1023;
        const size_t zbr = (size_t)b * 65536 + (size_t)m;
        const int    jjx = s_idx[lane];
        const float* er  = emb + ((size_t)jjx << 6);
        float* zq = out + OFF_ZQ + zbr;
#pragma unroll
        for (int p = 0; p < 2; ++p) {
            const int cls = q + 4 * p;
            float ls = 0.f;
#pragma unroll
            for (int i = 0; i < 8; ++i) {
                int c = cls + 8 * i;
                float zc   = z[zbr + (size_t)c * 1024];       // coalesced
                float ev   = er[c];                           // gather (L2)
                float diff = ev - zc;
                zq[(size_t)c * 1024] = zc + diff;             // zp + (z_q-zp)
                ls = fmaf(diff, diff, ls);
            }
#pragma unroll
            for (int off = 32; off >= 1; off >>= 1) ls += __shfl_down(ls, off);
            if (lane == 0) s_l[cls] = ls;
        }
        __syncthreads();
        if (t == 0) {
            float l = 0.f;
#pragma unroll
            for (int c = 0; c < 8; ++c) l += s_l[c];          // ascending
            partial[blockIdx.x] = l;
        }
    }
}

__global__ __launch_bounds__(1024) void vq_final(const int* __restrict__ hist,
                                                 const float* __restrict__ partial,
                                                 float* __restrict__ out) {
    int t = threadIdx.x;
    float p    = (float)hist[t] * (1.0f / 32768.0f);
    float term = p * logf(p + 1e-10f);
    float lp   = (t < NPART) ? partial[t] : 0.f;
#pragma unroll
    for (int off = 32; off >= 1; off >>= 1) {
        term += __shfl_down(term, off);
        lp   += __shfl_down(lp, off);
    }
    __shared__ float st[16], sl[16];
    int w = t >> 6, ln = t & 63;
    if (ln == 0) { st[w] = term; sl[w] = lp; }
    __syncthreads();
    if (t == 0) {
        float s = 0.f, l = 0.f;
#pragma unroll
        for (int i = 0; i < 16; ++i) { s += st[i]; l += sl[i]; }
        out[OFF_LOSS] = 1.25f * l * (1.0f / 2097152.0f);  // (1+beta)*mean
        out[OFF_PERP] = expf(-s);
    }
}

extern "C" void kernel_launch(void* const* d_in, const int* in_sizes, int n_in,
                              void* d_out, int out_size, void* d_ws, size_t ws_size,
                              hipStream_t stream) {
    const float* z   = (const float*)d_in[0];
    const float* emb = (const float*)d_in[1];
    float* out     = (float*)d_out;
    int*   hist    = (int*)d_ws;
    float* partial = (float*)((char*)d_ws + 4096);
    float* e2buf   = (float*)((char*)d_ws + 8192);

    vq_e2<<<8, 128, 0, stream>>>(emb, e2buf, hist);
    vq_scan<<<GRID_A, TPB_A, 0, stream>>>(z, emb, e2buf, out);
    vq_epi<<<GRID_B, TPB_B, 0, stream>>>(z, emb, hist, partial, out);
    vq_final<<<1, 1024, 0, stream>>>(hist, partial, out);
}